// Round 1
// baseline (729.622 us; speedup 1.0000x reference)
//
#include <hip/hip_runtime.h>

#define THREADS 256
#define NF 14   // input features
#define DIMOUT 16  // output dim

// ---- detect whether edge_index buffer is int64 (odd int32 words all zero) ----
__global__ void k_detect(const int* __restrict__ e32, int* __restrict__ flag) {
    int is64 = 1;
    for (int i = 1; i < 64; i += 2) {
        if (e32[i] != 0) { is64 = 0; break; }
    }
    *flag = is64;
}

// ---- count in-degree (real edges only; self-loop added later as +1) ----
__global__ void k_count(const void* __restrict__ edges, const int* __restrict__ flag,
                        int* __restrict__ counts, int E) {
    const bool is64 = (*flag != 0);
    const long long* e64 = (const long long*)edges;
    const int* e32 = (const int*)edges;
    int stride = gridDim.x * blockDim.x;
    for (int i = blockIdx.x * blockDim.x + threadIdx.x; i < E; i += stride) {
        int dst = is64 ? (int)e64[(size_t)E + i] : e32[(size_t)E + i];
        atomicAdd(&counts[dst], 1);
    }
}

// ---- single-block chunked exclusive scan + dinv = rsqrt(count+1) ----
__global__ __launch_bounds__(1024) void k_scan(const int* __restrict__ counts,
                                               int* __restrict__ offsets,
                                               float* __restrict__ dinv, int N, int E) {
    const int T = 1024;
    int tid = threadIdx.x;
    int items = (N + T - 1) / T;
    int beg = tid * items;
    int end = min(N, beg + items);
    int s = 0;
    for (int i = beg; i < end; ++i) s += counts[i];
    __shared__ int sm[T];
    sm[tid] = s;
    __syncthreads();
    // Hillis-Steele inclusive scan over per-thread totals
    for (int d = 1; d < T; d <<= 1) {
        int v = (tid >= d) ? sm[tid - d] : 0;
        __syncthreads();
        sm[tid] += v;
        __syncthreads();
    }
    int run = (tid > 0) ? sm[tid - 1] : 0;  // exclusive base
    for (int i = beg; i < end; ++i) {
        offsets[i] = run;
        dinv[i] = rsqrtf((float)(counts[i] + 1));
        run += counts[i];
    }
    if (tid == 0) offsets[N] = E;
}

// ---- fill CSR src lists ----
__global__ void k_fill(const void* __restrict__ edges, const int* __restrict__ flag,
                       const int* __restrict__ offsets, int* __restrict__ cursor,
                       int* __restrict__ srcs, int E) {
    const bool is64 = (*flag != 0);
    const long long* e64 = (const long long*)edges;
    const int* e32 = (const int*)edges;
    int stride = gridDim.x * blockDim.x;
    for (int i = blockIdx.x * blockDim.x + threadIdx.x; i < E; i += stride) {
        int src, dst;
        if (is64) {
            src = (int)e64[i];
            dst = (int)e64[(size_t)E + i];
        } else {
            src = e32[i];
            dst = e32[(size_t)E + i];
        }
        int pos = offsets[dst] + atomicAdd(&cursor[dst], 1);
        srcs[pos] = src;
    }
}

// ---- one propagation hop: 16-lane group per node, lane = feature ----
// FINAL=1 additionally applies out = x2 @ W^T + b via LDS transpose.
template <int FINAL>
__global__ void k_hop(const float* __restrict__ xin, const int* __restrict__ srcs,
                      const int* __restrict__ offsets, const float* __restrict__ dinv,
                      const float* __restrict__ W, const float* __restrict__ bias,
                      float* __restrict__ out, int N) {
    const int lane = threadIdx.x & 15;   // feature index (0..13 active)
    const int g = threadIdx.x >> 4;      // group within block (0..15)
    int n = blockIdx.x * 16 + g;
    float acc = 0.f;
    if (n < N) {
        float dn = dinv[n];
        int beg = offsets[n];
        int end = offsets[n + 1];
        float x_self = (lane < NF) ? xin[(size_t)n * NF + lane] : 0.f;
        acc = dn * x_self;  // self-loop contribution: dinv[n]^2 * x[n] (outer dn below)
        for (int e = beg; e < end; ++e) {
            int s = srcs[e];
            float xs = (lane < NF) ? xin[(size_t)s * NF + lane] : 0.f;
            acc += dinv[s] * xs;
        }
        acc *= dn;
    }
    if (!FINAL) {
        if (n < N && lane < NF) out[(size_t)n * NF + lane] = acc;
    } else {
        __shared__ float sm[16][16];
        sm[g][lane] = acc;  // lanes >= NF hold 0
        __syncthreads();
        if (n < N) {
            // lane = output dim j
            float r = bias[lane];
#pragma unroll
            for (int f = 0; f < NF; ++f) r += sm[g][f] * W[lane * NF + f];
            out[(size_t)n * DIMOUT + lane] = r;
        }
    }
}

extern "C" void kernel_launch(void* const* d_in, const int* in_sizes, int n_in,
                              void* d_out, int out_size, void* d_ws, size_t ws_size,
                              hipStream_t stream) {
    const float* x = (const float*)d_in[0];
    const void* edges = d_in[1];
    const float* W = (const float*)d_in[2];
    const float* b = (const float*)d_in[3];
    float* out = (float*)d_out;

    const int N = in_sizes[0] / NF;   // 100000
    const int E = in_sizes[1] / 2;    // 3200000

    char* ws = (char*)d_ws;
    size_t o = 0;
    auto alloc = [&](size_t bytes) -> void* {
        o = (o + 255) & ~(size_t)255;
        void* p = ws + o;
        o += bytes;
        return p;
    };
    int* flag = (int*)alloc(16);
    int* cz = (int*)alloc((size_t)2 * N * sizeof(int));  // counts | cursor, contiguous
    int* counts = cz;
    int* cursor = cz + N;
    int* offsets = (int*)alloc(((size_t)N + 1) * sizeof(int));
    float* dinv = (float*)alloc((size_t)N * sizeof(float));
    int* srcs = (int*)alloc((size_t)E * sizeof(int));
    float* x1 = (float*)alloc((size_t)N * NF * sizeof(float));
    (void)ws_size;
    (void)n_in;
    (void)out_size;

    hipMemsetAsync(cz, 0, (size_t)2 * N * sizeof(int), stream);
    k_detect<<<1, 1, 0, stream>>>((const int*)edges, flag);
    k_count<<<2048, THREADS, 0, stream>>>(edges, flag, counts, E);
    k_scan<<<1, 1024, 0, stream>>>(counts, offsets, dinv, N, E);
    k_fill<<<2048, THREADS, 0, stream>>>(edges, flag, offsets, cursor, srcs, E);

    int hopgrid = (N + 15) / 16;
    k_hop<0><<<hopgrid, 256, 0, stream>>>(x, srcs, offsets, dinv, nullptr, nullptr, x1, N);
    k_hop<1><<<hopgrid, 256, 0, stream>>>(x1, srcs, offsets, dinv, W, b, out, N);
}

// Round 2
// 463.963 us; speedup vs baseline: 1.5726x; 1.5726x over previous
//
#include <hip/hip_runtime.h>

#define THREADS 256
#define NF 14      // input features
#define DIMOUT 16  // output dim
#define SCAN_BLOCKS 256
#define SCAN_T 256

// ---- detect whether edge_index buffer is int64 (odd int32 words all zero) ----
__global__ void k_detect(const int* __restrict__ e32, int* __restrict__ flag) {
    int is64 = 1;
    for (int i = 1; i < 64; i += 2) {
        if (e32[i] != 0) { is64 = 0; break; }
    }
    *flag = is64;
}

// ---- count in-degree (real edges only; self-loop handled as +1 later) ----
__global__ void k_count(const void* __restrict__ edges, const int* __restrict__ flag,
                        int* __restrict__ counts, int E) {
    const bool is64 = (*flag != 0);
    const long long* e64 = (const long long*)edges;
    const int* e32 = (const int*)edges;
    int stride = gridDim.x * blockDim.x;
    for (int i = blockIdx.x * blockDim.x + threadIdx.x; i < E; i += stride) {
        int dst = is64 ? (int)e64[(size_t)E + i] : e32[(size_t)E + i];
        atomicAdd(&counts[dst], 1);
    }
}

// ---- scan phase A: per-block partial sums ----
__global__ __launch_bounds__(SCAN_T) void k_bsum(const int* __restrict__ counts,
                                                 int* __restrict__ bsum, int N) {
    int chunk = (N + SCAN_BLOCKS - 1) / SCAN_BLOCKS;
    int base = blockIdx.x * chunk;
    int endb = min(N, base + chunk);
    int ipt = (chunk + SCAN_T - 1) / SCAN_T;
    int t = threadIdx.x;
    int beg = base + t * ipt;
    int end = min(endb, beg + ipt);
    int s = 0;
    for (int i = beg; i < end; ++i) s += counts[i];
    __shared__ int sm[SCAN_T];
    sm[t] = s;
    __syncthreads();
    for (int d = SCAN_T / 2; d > 0; d >>= 1) {
        if (t < d) sm[t] += sm[t + d];
        __syncthreads();
    }
    if (t == 0) bsum[blockIdx.x] = sm[0];
}

// ---- scan phase B: exclusive scan of SCAN_BLOCKS partials (1 small block) ----
__global__ __launch_bounds__(SCAN_BLOCKS) void k_scanb(const int* __restrict__ bsum,
                                                       int* __restrict__ bbase) {
    __shared__ int sm[SCAN_BLOCKS];
    int t = threadIdx.x;
    sm[t] = bsum[t];
    __syncthreads();
    for (int d = 1; d < SCAN_BLOCKS; d <<= 1) {
        int v = (t >= d) ? sm[t - d] : 0;
        __syncthreads();
        sm[t] += v;
        __syncthreads();
    }
    bbase[t] = (t > 0) ? sm[t - 1] : 0;
}

// ---- scan phase C: write offsets + dinv ----
__global__ __launch_bounds__(SCAN_T) void k_woff(const int* __restrict__ counts,
                                                 const int* __restrict__ bbase,
                                                 int* __restrict__ offsets,
                                                 float* __restrict__ dinv, int N, int E) {
    int chunk = (N + SCAN_BLOCKS - 1) / SCAN_BLOCKS;
    int base = blockIdx.x * chunk;
    int endb = min(N, base + chunk);
    int ipt = (chunk + SCAN_T - 1) / SCAN_T;
    int t = threadIdx.x;
    int beg = base + t * ipt;
    int end = min(endb, beg + ipt);
    int s = 0;
    for (int i = beg; i < end; ++i) s += counts[i];
    __shared__ int sm[SCAN_T];
    sm[t] = s;
    __syncthreads();
    for (int d = 1; d < SCAN_T; d <<= 1) {
        int v = (t >= d) ? sm[t - d] : 0;
        __syncthreads();
        sm[t] += v;
        __syncthreads();
    }
    int run = bbase[blockIdx.x] + ((t > 0) ? sm[t - 1] : 0);
    for (int i = beg; i < end; ++i) {
        offsets[i] = run;
        dinv[i] = rsqrtf((float)(counts[i] + 1));
        run += counts[i];
    }
    if (blockIdx.x == 0 && t == 0) offsets[N] = E;
}

// ---- fill CSR src lists ----
__global__ void k_fill(const void* __restrict__ edges, const int* __restrict__ flag,
                       const int* __restrict__ offsets, int* __restrict__ cursor,
                       int* __restrict__ srcs, int E) {
    const bool is64 = (*flag != 0);
    const long long* e64 = (const long long*)edges;
    const int* e32 = (const int*)edges;
    int stride = gridDim.x * blockDim.x;
    for (int i = blockIdx.x * blockDim.x + threadIdx.x; i < E; i += stride) {
        int src, dst;
        if (is64) {
            src = (int)e64[i];
            dst = (int)e64[(size_t)E + i];
        } else {
            src = e32[i];
            dst = e32[(size_t)E + i];
        }
        int pos = offsets[dst] + atomicAdd(&cursor[dst], 1);
        srcs[pos] = src;
    }
}

// ---- one propagation hop: one wave per node, 4-way edge-parallel ----
// lane = ep*16 + feat; shfl_xor reduce across ep at the end.
// FINAL=1 additionally applies out = x2 @ W^T + b via LDS transpose.
template <int FINAL>
__global__ __launch_bounds__(256) void k_hop(const float* __restrict__ xin,
                                             const int* __restrict__ srcs,
                                             const int* __restrict__ offsets,
                                             const float* __restrict__ dinv,
                                             const float* __restrict__ W,
                                             const float* __restrict__ bias,
                                             float* __restrict__ out, int N) {
    const int lane = threadIdx.x & 63;
    const int feat = lane & 15;
    const int ep = lane >> 4;        // 0..3 edge-parallel subgroup
    const int g = threadIdx.x >> 6;  // wave in block (0..3)
    int n = blockIdx.x * 4 + g;
    float acc = 0.f;
    float dn = 0.f;
    if (n < N) {
        dn = dinv[n];
        int beg = offsets[n];
        int end = offsets[n + 1];
        if (ep == 0) {
            float xs = (feat < NF) ? xin[(size_t)n * NF + feat] : 0.f;
            acc = dn * xs;  // self-loop: dinv[n]^2 * x[n] (outer *dn below)
        }
        int e = beg + ep;
        // 2-way unrolled: two independent gathers in flight per sub-group
        for (; e + 4 < end; e += 8) {
            int s0 = srcs[e];
            int s1 = srcs[e + 4];
            float d0 = dinv[s0];
            float d1 = dinv[s1];
            float x0 = (feat < NF) ? xin[(size_t)s0 * NF + feat] : 0.f;
            float x1 = (feat < NF) ? xin[(size_t)s1 * NF + feat] : 0.f;
            acc += d0 * x0;
            acc += d1 * x1;
        }
        if (e < end) {
            int s0 = srcs[e];
            float xs = (feat < NF) ? xin[(size_t)s0 * NF + feat] : 0.f;
            acc += dinv[s0] * xs;
        }
    }
    acc += __shfl_xor(acc, 16);
    acc += __shfl_xor(acc, 32);
    acc *= dn;
    if (!FINAL) {
        if (n < N && ep == 0 && feat < NF) out[(size_t)n * NF + feat] = acc;
    } else {
        __shared__ float sm[4][16];
        if (ep == 0) sm[g][feat] = acc;  // feat>=NF lanes write 0
        __syncthreads();
        if (n < N && ep == 0) {
            float r = bias[feat];
#pragma unroll
            for (int f = 0; f < NF; ++f) r += sm[g][f] * W[feat * NF + f];
            out[(size_t)n * DIMOUT + feat] = r;
        }
    }
}

extern "C" void kernel_launch(void* const* d_in, const int* in_sizes, int n_in,
                              void* d_out, int out_size, void* d_ws, size_t ws_size,
                              hipStream_t stream) {
    const float* x = (const float*)d_in[0];
    const void* edges = d_in[1];
    const float* W = (const float*)d_in[2];
    const float* b = (const float*)d_in[3];
    float* out = (float*)d_out;

    const int N = in_sizes[0] / NF;   // 100000
    const int E = in_sizes[1] / 2;    // 3200000

    char* ws = (char*)d_ws;
    size_t o = 0;
    auto alloc = [&](size_t bytes) -> void* {
        o = (o + 255) & ~(size_t)255;
        void* p = ws + o;
        o += bytes;
        return p;
    };
    int* flag = (int*)alloc(16);
    int* cz = (int*)alloc((size_t)2 * N * sizeof(int));  // counts | cursor
    int* counts = cz;
    int* cursor = cz + N;
    int* offsets = (int*)alloc(((size_t)N + 1) * sizeof(int));
    float* dinv = (float*)alloc((size_t)N * sizeof(float));
    int* bsum = (int*)alloc((size_t)SCAN_BLOCKS * sizeof(int));
    int* bbase = (int*)alloc((size_t)SCAN_BLOCKS * sizeof(int));
    int* srcs = (int*)alloc((size_t)E * sizeof(int));
    float* x1 = (float*)alloc((size_t)N * NF * sizeof(float));
    (void)ws_size;
    (void)n_in;
    (void)out_size;

    hipMemsetAsync(cz, 0, (size_t)2 * N * sizeof(int), stream);
    k_detect<<<1, 1, 0, stream>>>((const int*)edges, flag);
    k_count<<<2048, THREADS, 0, stream>>>(edges, flag, counts, E);
    k_bsum<<<SCAN_BLOCKS, SCAN_T, 0, stream>>>(counts, bsum, N);
    k_scanb<<<1, SCAN_BLOCKS, 0, stream>>>(bsum, bbase);
    k_woff<<<SCAN_BLOCKS, SCAN_T, 0, stream>>>(counts, bbase, offsets, dinv, N, E);
    k_fill<<<2048, THREADS, 0, stream>>>(edges, flag, offsets, cursor, srcs, E);

    int hopgrid = (N + 3) / 4;
    k_hop<0><<<hopgrid, 256, 0, stream>>>(x, srcs, offsets, dinv, nullptr, nullptr, x1, N);
    k_hop<1><<<hopgrid, 256, 0, stream>>>(x1, srcs, offsets, dinv, W, b, out, N);
}